// Round 6
// baseline (4303.635 us; speedup 1.0000x reference)
//
#include <hip/hip_runtime.h>
#include <hip/hip_bf16.h>

#define D 128
#define NGRAPHS 64
#define NCLASSES 10
#define NB 800        // bucket array size (ceil(100000/128)=782, padded)
#define CAP 3072      // max edges per bucket (mean 2048, sigma~45 -> 22 sigma)
#define EPB 8192      // edges per k_bin block

typedef unsigned short u16;
typedef unsigned int u32;
typedef __attribute__((ext_vector_type(8))) short bf16x8;
typedef __attribute__((ext_vector_type(4))) float f32x4;

__device__ __forceinline__ u16 rne_bf16(float f) {
  u32 u = __float_as_uint(f);
  u += 0x7FFFu + ((u >> 16) & 1u);
  return (u16)(u >> 16);
}
__device__ __forceinline__ float bf_lo(u32 u) { return __uint_as_float(u << 16); }
__device__ __forceinline__ float bf_hi(u32 u) { return __uint_as_float(u & 0xFFFF0000u); }

// ================= f32 -> bf16 cast of x =================
__global__ __launch_bounds__(256) void k_cast0(const float* __restrict__ x,
                                               u16* __restrict__ xb, long long n8) {
  long long i = (long long)blockIdx.x * 256 + threadIdx.x;
  if (i >= n8) return;
  const float4* xp = reinterpret_cast<const float4*>(x) + i * 2;
  float4 a = xp[0], b = xp[1];
  u32 w0 = rne_bf16(a.x) | ((u32)rne_bf16(a.y) << 16);
  u32 w1 = rne_bf16(a.z) | ((u32)rne_bf16(a.w) << 16);
  u32 w2 = rne_bf16(b.x) | ((u32)rne_bf16(b.y) << 16);
  u32 w3 = rne_bf16(b.z) | ((u32)rne_bf16(b.w) << 16);
  reinterpret_cast<uint4*>(xb)[i] = make_uint4(w0, w1, w2, w3);
}

// ================= W[k][c] (f32) -> Wt[c][k] (bf16), 6 matrices =================
__global__ __launch_bounds__(256) void k_prep_wt(const float* __restrict__ W_rel,
                                                 const float* __restrict__ W_root,
                                                 u16* __restrict__ Wt) {
  int id = blockIdx.x * 256 + threadIdx.x;
  if (id >= 6 * D * D) return;
  int col = id & 127;
  int k = (id >> 7) & 127;
  int m = id >> 14;
  const float* src = (m < 3) ? (W_rel + (size_t)m * D * D) : (W_root + (size_t)(m - 3) * D * D);
  Wt[(size_t)m * D * D + col * D + k] = rne_bf16(src[k * D + col]);
}

// ================= edge binning into 128-node buckets =================
// Replaces exact CSR (hist+scan+fill, 1.6M atomic-returns on 100k addrs, 127us)
// with per-block batched reservation: 196 blocks x ~782 bins = 153k atomic-returns.
__global__ __launch_bounds__(256) void k_bin(
    const int* __restrict__ src, const int* __restrict__ dst,
    int* __restrict__ gcnt, u32* __restrict__ ebuf, int n_edges, int nb) {
  __shared__ int lh[NB];
  int tid = threadIdx.x;
  int e0 = blockIdx.x * EPB;
  for (int b = tid; b < NB; b += 256) lh[b] = 0;
  __syncthreads();
  for (int i = tid; i < EPB; i += 256) {
    int e = e0 + i;
    if (e < n_edges) atomicAdd(&lh[dst[e] >> 7], 1);
  }
  __syncthreads();
  // one global atomic-return per nonzero bin; lh[b] becomes this block's write cursor
  for (int b = tid; b < nb; b += 256) {
    int c = lh[b];
    lh[b] = (c > 0) ? (b * CAP + atomicAdd(&gcnt[b], c)) : 0;
  }
  __syncthreads();
  for (int i = tid; i < EPB; i += 256) {
    int e = e0 + i;
    if (e < n_edges) {
      int d = dst[e];
      int slot = atomicAdd(&lh[d >> 7], 1);          // LDS atomic-return (cheap)
      ebuf[slot] = ((u32)(d & 127) << 20) | (u32)src[e];
    }
  }
}

// ================= bucketed gather: LDS f32 accumulate, bf16 out =================
// One edge per wave; lane l owns features 2l,2l+1 -> ds_add_f32 banks (2l+j)%32
// = 2-way conflict (free, m136). x-row read = one coalesced 256B dword load/wave.
__global__ __launch_bounds__(256) void k_gather_b(
    const u16* __restrict__ xb, const u32* __restrict__ ebuf,
    const int* __restrict__ gcnt, u16* __restrict__ aggb, int n_nodes) {
  __shared__ float accf[128 * D];   // 64KB -> 2 blocks/CU
  int tid = threadIdx.x;
  int lane = tid & 63;
  int wave = tid >> 6;
  int bkt = blockIdx.x;
  int col = lane * 2;
  for (int i = tid; i < 128 * D; i += 256) accf[i] = 0.f;
  __syncthreads();
  int cnt = gcnt[bkt];
  int base = bkt * CAP;
  for (int i0 = wave; i0 < cnt; i0 += 16) {   // 4 waves, 4 edges in flight each
    u32 vv[4]; int dl[4]; bool pr[4];
    #pragma unroll
    for (int u = 0; u < 4; u++) {
      int idx = i0 + u * 4;
      pr[u] = idx < cnt;
      u32 e = pr[u] ? ebuf[base + idx] : 0u;
      dl[u] = (int)(e >> 20);
      int s = (int)(e & 0xFFFFF);
      vv[u] = pr[u] ? *reinterpret_cast<const u32*>(xb + (size_t)s * D + col) : 0u;
    }
    #pragma unroll
    for (int u = 0; u < 4; u++) {
      if (pr[u]) {
        atomicAdd(&accf[dl[u] * D + col], bf_lo(vv[u]));
        atomicAdd(&accf[dl[u] * D + col + 1], bf_hi(vv[u]));
      }
    }
  }
  __syncthreads();
  // write out: same lane->feature mapping (conflict-free), coalesced 256B stores
  int n0 = bkt * 128;
  for (int r = wave; r < 128; r += 4) {
    int n = n0 + r;
    if (n < n_nodes) {
      float f0 = accf[r * D + col];
      float f1 = accf[r * D + col + 1];
      u32 w = (u32)rne_bf16(f0) | ((u32)rne_bf16(f1) << 16);
      *reinterpret_cast<u32*>(aggb + (size_t)n * D + col) = w;
    }
  }
}

// ================= MFMA dual GEMM: out = A1@W1 + A2@W2 + bias (bf16, f32 acc) =====
__global__ __launch_bounds__(256) void k_gemm_mfma(
    const u16* __restrict__ A1, const u16* __restrict__ A2,
    const u16* __restrict__ Wt1, const u16* __restrict__ Wt2,
    const float* __restrict__ bias, u16* __restrict__ outp, int M) {
  __shared__ __align__(16) u16 As[128 * 64];
  __shared__ __align__(16) u16 Ws[128 * 64];
  int tid = threadIdx.x;
  int wave = tid >> 6, lane = tid & 63;
  int g = lane >> 4, lr = lane & 15;
  int r0 = blockIdx.x * 128;
  int wr = wave * 32;

  f32x4 acc[2][8];
  #pragma unroll
  for (int fr = 0; fr < 2; fr++)
    #pragma unroll
    for (int fc = 0; fc < 8; fc++)
      acc[fr][fc] = (f32x4){0.f, 0.f, 0.f, 0.f};

  int srow = tid >> 1;
  int shalf = tid & 1;

  #pragma unroll 1
  for (int pass = 0; pass < 2; pass++) {
    const u16* A = pass ? A2 : A1;
    const u16* Wt = pass ? Wt2 : Wt1;
    #pragma unroll 1
    for (int kh = 0; kh < 2; kh++) {
      int rg = r0 + srow; if (rg >= M) rg = M - 1;
      const u16* ga = A + (size_t)rg * D + kh * 64 + shalf * 32;
      const u16* gw = Wt + (size_t)srow * D + kh * 64 + shalf * 32;
      #pragma unroll
      for (int cch = 0; cch < 4; cch++) {
        int boff = ((shalf * 64 + cch * 16) ^ ((srow & 7) << 4)) >> 1;  // in u16
        uint4 va = *reinterpret_cast<const uint4*>(ga + cch * 8);
        *reinterpret_cast<uint4*>(&As[srow * 64 + boff]) = va;
        uint4 vw = *reinterpret_cast<const uint4*>(gw + cch * 8);
        *reinterpret_cast<uint4*>(&Ws[srow * 64 + boff]) = vw;
      }
      __syncthreads();
      #pragma unroll
      for (int kc = 0; kc < 2; kc++) {
        int kbyte = kc * 64 + g * 16;
        bf16x8 af[2];
        #pragma unroll
        for (int fr = 0; fr < 2; fr++) {
          int row = wr + fr * 16 + lr;
          int ob = (kbyte ^ ((row & 7) << 4)) >> 1;
          af[fr] = *reinterpret_cast<const bf16x8*>(&As[row * 64 + ob]);
        }
        #pragma unroll
        for (int fc = 0; fc < 8; fc++) {
          int colw = fc * 16 + lr;
          int ob = (kbyte ^ ((colw & 7) << 4)) >> 1;
          bf16x8 bfv = *reinterpret_cast<const bf16x8*>(&Ws[colw * 64 + ob]);
          #pragma unroll
          for (int fr = 0; fr < 2; fr++)
            acc[fr][fc] = __builtin_amdgcn_mfma_f32_16x16x32_bf16(
                af[fr], bfv, acc[fr][fc], 0, 0, 0);
        }
      }
      __syncthreads();
    }
  }

  #pragma unroll
  for (int fc = 0; fc < 8; fc++) {
    float bc = bias[fc * 16 + lr];
    #pragma unroll
    for (int fr = 0; fr < 2; fr++) {
      #pragma unroll
      for (int j = 0; j < 4; j++) {
        int R = r0 + wr + fr * 16 + g * 4 + j;
        if (R < M)
          outp[(size_t)R * D + fc * 16 + lr] = rne_bf16(acc[fr][fc][j] + bc);
      }
    }
  }
}

// ================= mean pool (batch sorted, bf16 input) =================
#define CHUNK 256
__global__ __launch_bounds__(256) void k_pool(
    const u16* __restrict__ xb, const int* __restrict__ batch,
    float* __restrict__ pooled, int n_nodes) {
  int col = threadIdx.x & 127;
  int sub = threadIdx.x >> 7;
  int n0 = blockIdx.x * CHUNK;
  int nend = min(n0 + CHUNK, n_nodes);
  float sum = 0.f; int cur = -1;
  for (int n = n0 + sub; n < nend; n += 2) {
    int g = batch[n];
    if (g != cur) {
      if (cur >= 0) atomicAdd(&pooled[cur * D + col], sum);
      sum = 0.f; cur = g;
    }
    sum += __uint_as_float((u32)xb[(size_t)n * D + col] << 16);
  }
  if (cur >= 0) atomicAdd(&pooled[cur * D + col], sum);
}

// ================= graph start markers (batch sorted) =================
__global__ __launch_bounds__(256) void k_bounds(
    const int* __restrict__ batch, int* __restrict__ start, int n) {
  int i = blockIdx.x * 256 + threadIdx.x;
  if (i >= n) return;
  int g = batch[i];
  if (i == 0 || batch[i - 1] != g) start[g] = i;
}

// ================= head (computes counts from start markers) =================
__global__ void k_head(const float* __restrict__ pooled, const int* __restrict__ gstart,
                       const float* __restrict__ W_fc, const float* __restrict__ b_fc,
                       float* __restrict__ outp, int n_nodes) {
  int g = threadIdx.x;
  if (g >= NGRAPHS) return;
  int s = gstart[g];
  int c = 0;
  if (s >= 0) {
    int e = n_nodes;
    for (int h = g + 1; h < NGRAPHS; h++)
      if (gstart[h] >= 0) { e = gstart[h]; break; }
    c = e - s;
  }
  float inv = 1.0f / fmaxf((float)c, 1.0f);
  float logits[NCLASSES];
  #pragma unroll
  for (int j = 0; j < NCLASSES; j++) logits[j] = b_fc[j];
  for (int k = 0; k < D; k++) {
    float p = pooled[g * D + k] * inv;
    #pragma unroll
    for (int j = 0; j < NCLASSES; j++) logits[j] += p * W_fc[k * NCLASSES + j];
  }
  float m = logits[0];
  #pragma unroll
  for (int j = 1; j < NCLASSES; j++) m = fmaxf(m, logits[j]);
  float s2 = 0.f;
  #pragma unroll
  for (int j = 0; j < NCLASSES; j++) s2 += expf(logits[j] - m);
  float lse = m + logf(s2);
  #pragma unroll
  for (int j = 0; j < NCLASSES; j++) outp[g * NCLASSES + j] = logits[j] - lse;
}

extern "C" void kernel_launch(void* const* d_in, const int* in_sizes, int n_in,
                              void* d_out, int out_size, void* d_ws, size_t ws_size,
                              hipStream_t stream) {
  const float* x      = (const float*)d_in[0];
  const int*   ei     = (const int*)d_in[1];
  const int*   batch  = (const int*)d_in[2];
  const float* W_rel  = (const float*)d_in[3];
  const float* W_root = (const float*)d_in[4];
  const float* b_rel  = (const float*)d_in[5];
  const float* W_fc   = (const float*)d_in[6];
  const float* b_fc   = (const float*)d_in[7];
  float* outp = (float*)d_out;

  int n_nodes = in_sizes[0] / D;
  int n_edges = in_sizes[1] / 2;
  const int* src = ei;
  const int* dst = ei + n_edges;
  int nb = (n_nodes + 127) / 128;   // 782

  char* ws = (char*)d_ws;
  size_t bb = (size_t)n_nodes * D * sizeof(u16);   // 25.6 MB
  u16* aggb   = (u16*)(ws);
  u16* xba    = (u16*)(ws + bb);
  u16* xbb    = (u16*)(ws + 2 * bb);
  char* p     = ws + 3 * bb;
  u16* Wt     = (u16*)(p);               p += (size_t)6 * D * D * sizeof(u16);
  int* gcnt   = (int*)(p);               p += (size_t)NB * sizeof(int);
  u32* ebuf   = (u32*)(p);               p += (size_t)NB * CAP * sizeof(u32);
  float* pooled = (float*)(p);           p += (size_t)NGRAPHS * D * sizeof(float);
  int* gstart = (int*)(p);

  // prep: weight transpose+cast, x cast, bucket binning
  k_prep_wt<<<(6 * D * D + 255) / 256, 256, 0, stream>>>(W_rel, W_root, Wt);
  long long n8 = (long long)n_nodes * D / 8;
  k_cast0<<<(int)((n8 + 255) / 256), 256, 0, stream>>>(x, xba, n8);
  hipMemsetAsync(gcnt, 0, (size_t)NB * sizeof(int), stream);
  k_bin<<<(n_edges + EPB - 1) / EPB, 256, 0, stream>>>(src, dst, gcnt, ebuf, n_edges, nb);

  // 3 GraphConv layers
  u16* xc = xba;
  u16* xn = xbb;
  int gemmblk = (n_nodes + 127) / 128;
  for (int l = 0; l < 3; l++) {
    k_gather_b<<<nb, 256, 0, stream>>>(xc, ebuf, gcnt, aggb, n_nodes);
    k_gemm_mfma<<<gemmblk, 256, 0, stream>>>(
        aggb, xc, Wt + (size_t)l * D * D, Wt + (size_t)(3 + l) * D * D,
        b_rel + (size_t)l * D, xn, n_nodes);
    u16* t = xc; xc = xn; xn = t;
  }

  // pool + head
  hipMemsetAsync(pooled, 0, (size_t)NGRAPHS * D * sizeof(float), stream);
  hipMemsetAsync(gstart, 0xFF, (size_t)NGRAPHS * sizeof(int), stream);
  k_pool<<<(n_nodes + CHUNK - 1) / CHUNK, 256, 0, stream>>>(xc, batch, pooled, n_nodes);
  k_bounds<<<(n_nodes + 255) / 256, 256, 0, stream>>>(batch, gstart, n_nodes);
  k_head<<<1, 64, 0, stream>>>(pooled, gstart, W_fc, b_fc, outp, n_nodes);
}

// Round 7
// 547.847 us; speedup vs baseline: 7.8555x; 7.8555x over previous
//
#include <hip/hip_runtime.h>
#include <hip/hip_bf16.h>

#define D 128
#define NGRAPHS 64
#define NCLASSES 10
#define NB 800        // bucket array size (ceil(100000/128)=782, padded)
#define CAP 3072      // max edges per bucket (mean 2048, sigma~45 -> 22 sigma)
#define EPB 8192      // edges per k_bin block

typedef unsigned short u16;
typedef unsigned int u32;
typedef __attribute__((ext_vector_type(8))) short bf16x8;
typedef __attribute__((ext_vector_type(4))) float f32x4;

__device__ __forceinline__ u16 rne_bf16(float f) {
  u32 u = __float_as_uint(f);
  u += 0x7FFFu + ((u >> 16) & 1u);
  return (u16)(u >> 16);
}
__device__ __forceinline__ float bf_lo(u32 u) { return __uint_as_float(u << 16); }
__device__ __forceinline__ float bf_hi(u32 u) { return __uint_as_float(u & 0xFFFF0000u); }

// ================= f32 -> bf16 cast of x =================
__global__ __launch_bounds__(256) void k_cast0(const float* __restrict__ x,
                                               u16* __restrict__ xb, long long n8) {
  long long i = (long long)blockIdx.x * 256 + threadIdx.x;
  if (i >= n8) return;
  const float4* xp = reinterpret_cast<const float4*>(x) + i * 2;
  float4 a = xp[0], b = xp[1];
  u32 w0 = rne_bf16(a.x) | ((u32)rne_bf16(a.y) << 16);
  u32 w1 = rne_bf16(a.z) | ((u32)rne_bf16(a.w) << 16);
  u32 w2 = rne_bf16(b.x) | ((u32)rne_bf16(b.y) << 16);
  u32 w3 = rne_bf16(b.z) | ((u32)rne_bf16(b.w) << 16);
  reinterpret_cast<uint4*>(xb)[i] = make_uint4(w0, w1, w2, w3);
}

// ================= W[k][c] (f32) -> Wt[c][k] (bf16), 6 matrices =================
__global__ __launch_bounds__(256) void k_prep_wt(const float* __restrict__ W_rel,
                                                 const float* __restrict__ W_root,
                                                 u16* __restrict__ Wt) {
  int id = blockIdx.x * 256 + threadIdx.x;
  if (id >= 6 * D * D) return;
  int col = id & 127;
  int k = (id >> 7) & 127;
  int m = id >> 14;
  const float* src = (m < 3) ? (W_rel + (size_t)m * D * D) : (W_root + (size_t)(m - 3) * D * D);
  Wt[(size_t)m * D * D + col * D + k] = rne_bf16(src[k * D + col]);
}

// ================= edge binning into 128-node buckets (validated round 6) ==========
// LDS histogram + batched reservation: 196 blocks x 782 bins = 153k atomic-returns
// (vs exact-CSR k_fill's 1.6M on 100k addresses = 127us).
__global__ __launch_bounds__(256) void k_bin(
    const int* __restrict__ src, const int* __restrict__ dst,
    int* __restrict__ gcnt, u32* __restrict__ ebuf, int n_edges, int nb) {
  __shared__ int lh[NB];
  int tid = threadIdx.x;
  int e0 = blockIdx.x * EPB;
  for (int b = tid; b < NB; b += 256) lh[b] = 0;
  __syncthreads();
  for (int i = tid; i < EPB; i += 256) {
    int e = e0 + i;
    if (e < n_edges) atomicAdd(&lh[dst[e] >> 7], 1);
  }
  __syncthreads();
  for (int b = tid; b < nb; b += 256) {
    int c = lh[b];
    lh[b] = (c > 0) ? (b * CAP + atomicAdd(&gcnt[b], c)) : 0;
  }
  __syncthreads();
  for (int i = tid; i < EPB; i += 256) {
    int e = e0 + i;
    if (e < n_edges) {
      int d = dst[e];
      int slot = atomicAdd(&lh[d >> 7], 1);          // LDS atomic-return (cheap)
      ebuf[slot] = ((u32)(d & 127) << 20) | (u32)src[e];
    }
  }
}

// ================= per-bucket sort -> exact CSR (rowptr/deg/eidx) =================
// One block per bucket: <=3072 edges in 12KB LDS, 128-counter histogram,
// 7-step LDS scan, LDS-cursor scatter. Zero global atomics.
__global__ __launch_bounds__(256) void k_sort(
    const u32* __restrict__ ebuf, const int* __restrict__ gcnt,
    u32* __restrict__ eidx, int* __restrict__ rowptr, int* __restrict__ deg,
    int n_nodes) {
  __shared__ u32 earr[CAP];
  __shared__ int lh[128], sc[128], lcur[128];
  int tid = threadIdx.x;
  int b = blockIdx.x;
  int cnt = gcnt[b];
  int base = b * CAP;
  for (int i = tid; i < cnt; i += 256) earr[i] = ebuf[base + i];
  if (tid < 128) lh[tid] = 0;
  __syncthreads();
  for (int i = tid; i < cnt; i += 256) atomicAdd(&lh[earr[i] >> 20], 1);
  __syncthreads();
  if (tid < 128) sc[tid] = lh[tid];
  __syncthreads();
  #pragma unroll
  for (int off = 1; off < 128; off <<= 1) {
    int v = (tid < 128 && tid >= off) ? sc[tid - off] : 0;
    __syncthreads();
    if (tid < 128) sc[tid] += v;
    __syncthreads();
  }
  if (tid < 128) {
    int excl = sc[tid] - lh[tid];
    int n = b * 128 + tid;
    if (n < n_nodes) { rowptr[n] = base + excl; deg[n] = lh[tid]; }
    lcur[tid] = excl;
  }
  __syncthreads();
  for (int i = tid; i < cnt; i += 256) {
    u32 e = earr[i];
    int slot = atomicAdd(&lcur[e >> 20], 1);
    eidx[base + slot] = e & 0xFFFFF;
  }
}

// ================= gather (bf16, per-node, high occupancy — round-5 form) ==========
__global__ __launch_bounds__(256) void k_gather(
    const u16* __restrict__ xb, const int* __restrict__ rowptr,
    const int* __restrict__ deg, const u32* __restrict__ eidx,
    u16* __restrict__ aggb, int n_nodes) {
  int tid = threadIdx.x;
  int n = blockIdx.x * 16 + (tid >> 4);
  int c = tid & 15;                        // 16B chunk (8 bf16) within the 256B row
  if (n >= n_nodes) return;
  int beg = rowptr[n];
  int dn = deg[n];
  float a0 = 0, a1 = 0, a2 = 0, a3 = 0, a4 = 0, a5 = 0, a6 = 0, a7 = 0;
  for (int i = 0; i < dn; i++) {
    int s = (int)eidx[beg + i];
    uint4 v = *(reinterpret_cast<const uint4*>(xb + (size_t)s * D) + c);
    a0 += bf_lo(v.x); a1 += bf_hi(v.x);
    a2 += bf_lo(v.y); a3 += bf_hi(v.y);
    a4 += bf_lo(v.z); a5 += bf_hi(v.z);
    a6 += bf_lo(v.w); a7 += bf_hi(v.w);
  }
  u32 w0 = rne_bf16(a0) | ((u32)rne_bf16(a1) << 16);
  u32 w1 = rne_bf16(a2) | ((u32)rne_bf16(a3) << 16);
  u32 w2 = rne_bf16(a4) | ((u32)rne_bf16(a5) << 16);
  u32 w3 = rne_bf16(a6) | ((u32)rne_bf16(a7) << 16);
  *(reinterpret_cast<uint4*>(aggb + (size_t)n * D) + c) = make_uint4(w0, w1, w2, w3);
}

// ================= MFMA dual GEMM: out = A1@W1 + A2@W2 + bias (bf16, f32 acc) =====
__global__ __launch_bounds__(256) void k_gemm_mfma(
    const u16* __restrict__ A1, const u16* __restrict__ A2,
    const u16* __restrict__ Wt1, const u16* __restrict__ Wt2,
    const float* __restrict__ bias, u16* __restrict__ outp, int M) {
  __shared__ __align__(16) u16 As[128 * 64];
  __shared__ __align__(16) u16 Ws[128 * 64];
  int tid = threadIdx.x;
  int wave = tid >> 6, lane = tid & 63;
  int g = lane >> 4, lr = lane & 15;
  int r0 = blockIdx.x * 128;
  int wr = wave * 32;

  f32x4 acc[2][8];
  #pragma unroll
  for (int fr = 0; fr < 2; fr++)
    #pragma unroll
    for (int fc = 0; fc < 8; fc++)
      acc[fr][fc] = (f32x4){0.f, 0.f, 0.f, 0.f};

  int srow = tid >> 1;
  int shalf = tid & 1;

  #pragma unroll 1
  for (int pass = 0; pass < 2; pass++) {
    const u16* A = pass ? A2 : A1;
    const u16* Wt = pass ? Wt2 : Wt1;
    #pragma unroll 1
    for (int kh = 0; kh < 2; kh++) {
      int rg = r0 + srow; if (rg >= M) rg = M - 1;
      const u16* ga = A + (size_t)rg * D + kh * 64 + shalf * 32;
      const u16* gw = Wt + (size_t)srow * D + kh * 64 + shalf * 32;
      #pragma unroll
      for (int cch = 0; cch < 4; cch++) {
        int boff = ((shalf * 64 + cch * 16) ^ ((srow & 7) << 4)) >> 1;  // in u16
        uint4 va = *reinterpret_cast<const uint4*>(ga + cch * 8);
        *reinterpret_cast<uint4*>(&As[srow * 64 + boff]) = va;
        uint4 vw = *reinterpret_cast<const uint4*>(gw + cch * 8);
        *reinterpret_cast<uint4*>(&Ws[srow * 64 + boff]) = vw;
      }
      __syncthreads();
      #pragma unroll
      for (int kc = 0; kc < 2; kc++) {
        int kbyte = kc * 64 + g * 16;
        bf16x8 af[2];
        #pragma unroll
        for (int fr = 0; fr < 2; fr++) {
          int row = wr + fr * 16 + lr;
          int ob = (kbyte ^ ((row & 7) << 4)) >> 1;
          af[fr] = *reinterpret_cast<const bf16x8*>(&As[row * 64 + ob]);
        }
        #pragma unroll
        for (int fc = 0; fc < 8; fc++) {
          int colw = fc * 16 + lr;
          int ob = (kbyte ^ ((colw & 7) << 4)) >> 1;
          bf16x8 bfv = *reinterpret_cast<const bf16x8*>(&Ws[colw * 64 + ob]);
          #pragma unroll
          for (int fr = 0; fr < 2; fr++)
            acc[fr][fc] = __builtin_amdgcn_mfma_f32_16x16x32_bf16(
                af[fr], bfv, acc[fr][fc], 0, 0, 0);
        }
      }
      __syncthreads();
    }
  }

  #pragma unroll
  for (int fc = 0; fc < 8; fc++) {
    float bc = bias[fc * 16 + lr];
    #pragma unroll
    for (int fr = 0; fr < 2; fr++) {
      #pragma unroll
      for (int j = 0; j < 4; j++) {
        int R = r0 + wr + fr * 16 + g * 4 + j;
        if (R < M)
          outp[(size_t)R * D + fc * 16 + lr] = rne_bf16(acc[fr][fc][j] + bc);
      }
    }
  }
}

// ================= mean pool (batch sorted, bf16 input) =================
#define CHUNK 256
__global__ __launch_bounds__(256) void k_pool(
    const u16* __restrict__ xb, const int* __restrict__ batch,
    float* __restrict__ pooled, int n_nodes) {
  int col = threadIdx.x & 127;
  int sub = threadIdx.x >> 7;
  int n0 = blockIdx.x * CHUNK;
  int nend = min(n0 + CHUNK, n_nodes);
  float sum = 0.f; int cur = -1;
  for (int n = n0 + sub; n < nend; n += 2) {
    int g = batch[n];
    if (g != cur) {
      if (cur >= 0) atomicAdd(&pooled[cur * D + col], sum);
      sum = 0.f; cur = g;
    }
    sum += __uint_as_float((u32)xb[(size_t)n * D + col] << 16);
  }
  if (cur >= 0) atomicAdd(&pooled[cur * D + col], sum);
}

// ================= graph start markers (batch sorted) =================
__global__ __launch_bounds__(256) void k_bounds(
    const int* __restrict__ batch, int* __restrict__ start, int n) {
  int i = blockIdx.x * 256 + threadIdx.x;
  if (i >= n) return;
  int g = batch[i];
  if (i == 0 || batch[i - 1] != g) start[g] = i;
}

// ================= head (computes counts from start markers) =================
__global__ void k_head(const float* __restrict__ pooled, const int* __restrict__ gstart,
                       const float* __restrict__ W_fc, const float* __restrict__ b_fc,
                       float* __restrict__ outp, int n_nodes) {
  int g = threadIdx.x;
  if (g >= NGRAPHS) return;
  int s = gstart[g];
  int c = 0;
  if (s >= 0) {
    int e = n_nodes;
    for (int h = g + 1; h < NGRAPHS; h++)
      if (gstart[h] >= 0) { e = gstart[h]; break; }
    c = e - s;
  }
  float inv = 1.0f / fmaxf((float)c, 1.0f);
  float logits[NCLASSES];
  #pragma unroll
  for (int j = 0; j < NCLASSES; j++) logits[j] = b_fc[j];
  for (int k = 0; k < D; k++) {
    float p = pooled[g * D + k] * inv;
    #pragma unroll
    for (int j = 0; j < NCLASSES; j++) logits[j] += p * W_fc[k * NCLASSES + j];
  }
  float m = logits[0];
  #pragma unroll
  for (int j = 1; j < NCLASSES; j++) m = fmaxf(m, logits[j]);
  float s2 = 0.f;
  #pragma unroll
  for (int j = 0; j < NCLASSES; j++) s2 += expf(logits[j] - m);
  float lse = m + logf(s2);
  #pragma unroll
  for (int j = 0; j < NCLASSES; j++) outp[g * NCLASSES + j] = logits[j] - lse;
}

extern "C" void kernel_launch(void* const* d_in, const int* in_sizes, int n_in,
                              void* d_out, int out_size, void* d_ws, size_t ws_size,
                              hipStream_t stream) {
  const float* x      = (const float*)d_in[0];
  const int*   ei     = (const int*)d_in[1];
  const int*   batch  = (const int*)d_in[2];
  const float* W_rel  = (const float*)d_in[3];
  const float* W_root = (const float*)d_in[4];
  const float* b_rel  = (const float*)d_in[5];
  const float* W_fc   = (const float*)d_in[6];
  const float* b_fc   = (const float*)d_in[7];
  float* outp = (float*)d_out;

  int n_nodes = in_sizes[0] / D;
  int n_edges = in_sizes[1] / 2;
  const int* src = ei;
  const int* dst = ei + n_edges;
  int nb = (n_nodes + 127) / 128;   // 782

  char* ws = (char*)d_ws;
  size_t bb = (size_t)n_nodes * D * sizeof(u16);   // 25.6 MB
  size_t nbts = (size_t)n_nodes * sizeof(int);
  u16* aggb   = (u16*)(ws);
  u16* xba    = (u16*)(ws + bb);
  u16* xbb    = (u16*)(ws + 2 * bb);
  char* p     = ws + 3 * bb;
  u16* Wt     = (u16*)(p);               p += (size_t)6 * D * D * sizeof(u16);
  int* gcnt   = (int*)(p);               p += (size_t)NB * sizeof(int);
  u32* ebuf   = (u32*)(p);               p += (size_t)NB * CAP * sizeof(u32);
  u32* eidx   = (u32*)(p);               p += (size_t)NB * CAP * sizeof(u32);
  int* rowptr = (int*)(p);               p += nbts;
  int* deg    = (int*)(p);               p += nbts;
  float* pooled = (float*)(p);           p += (size_t)NGRAPHS * D * sizeof(float);
  int* gstart = (int*)(p);

  // prep: weight transpose+cast, x cast, bucket binning + per-bucket CSR sort
  k_prep_wt<<<(6 * D * D + 255) / 256, 256, 0, stream>>>(W_rel, W_root, Wt);
  long long n8 = (long long)n_nodes * D / 8;
  k_cast0<<<(int)((n8 + 255) / 256), 256, 0, stream>>>(x, xba, n8);
  hipMemsetAsync(gcnt, 0, (size_t)NB * sizeof(int), stream);
  k_bin<<<(n_edges + EPB - 1) / EPB, 256, 0, stream>>>(src, dst, gcnt, ebuf, n_edges, nb);
  k_sort<<<nb, 256, 0, stream>>>(ebuf, gcnt, eidx, rowptr, deg, n_nodes);

  // 3 GraphConv layers
  u16* xc = xba;
  u16* xn = xbb;
  int gemmblk = (n_nodes + 127) / 128;
  for (int l = 0; l < 3; l++) {
    k_gather<<<(n_nodes + 15) / 16, 256, 0, stream>>>(xc, rowptr, deg, eidx, aggb, n_nodes);
    k_gemm_mfma<<<gemmblk, 256, 0, stream>>>(
        aggb, xc, Wt + (size_t)l * D * D, Wt + (size_t)(3 + l) * D * D,
        b_rel + (size_t)l * D, xn, n_nodes);
    u16* t = xc; xc = xn; xn = t;
  }

  // pool + head
  hipMemsetAsync(pooled, 0, (size_t)NGRAPHS * D * sizeof(float), stream);
  hipMemsetAsync(gstart, 0xFF, (size_t)NGRAPHS * sizeof(int), stream);
  k_pool<<<(n_nodes + CHUNK - 1) / CHUNK, 256, 0, stream>>>(xc, batch, pooled, n_nodes);
  k_bounds<<<(n_nodes + 255) / 256, 256, 0, stream>>>(batch, gstart, n_nodes);
  k_head<<<1, 64, 0, stream>>>(pooled, gstart, W_fc, b_fc, outp, n_nodes);
}

// Round 8
// 497.357 us; speedup vs baseline: 8.6530x; 1.1015x over previous
//
#include <hip/hip_runtime.h>
#include <hip/hip_bf16.h>

#define D 128
#define NGRAPHS 64
#define NCLASSES 10
#define NB 800        // bucket array size (ceil(100000/128)=782, padded)
#define CAP 3072      // max edges per bucket (mean 2048, sigma~45 -> 22 sigma)
#define EPB 8192      // edges per k_bin block

typedef unsigned short u16;
typedef unsigned int u32;
typedef __attribute__((ext_vector_type(8))) short bf16x8;
typedef __attribute__((ext_vector_type(4))) float f32x4;

__device__ __forceinline__ u16 rne_bf16(float f) {
  u32 u = __float_as_uint(f);
  u += 0x7FFFu + ((u >> 16) & 1u);
  return (u16)(u >> 16);
}
__device__ __forceinline__ float bf_lo(u32 u) { return __uint_as_float(u << 16); }
__device__ __forceinline__ float bf_hi(u32 u) { return __uint_as_float(u & 0xFFFF0000u); }

// async global->LDS, 16B per lane, dest = wave-uniform base + lane*16
__device__ __forceinline__ void gload_lds16(const void* g, void* l) {
  __builtin_amdgcn_global_load_lds(
      (const __attribute__((address_space(1))) void*)g,
      (__attribute__((address_space(3))) void*)l, 16, 0, 0);
}

// ================= f32 -> bf16 cast of x =================
__global__ __launch_bounds__(256) void k_cast0(const float* __restrict__ x,
                                               u16* __restrict__ xb, long long n8) {
  long long i = (long long)blockIdx.x * 256 + threadIdx.x;
  if (i >= n8) return;
  const float4* xp = reinterpret_cast<const float4*>(x) + i * 2;
  float4 a = xp[0], b = xp[1];
  u32 w0 = rne_bf16(a.x) | ((u32)rne_bf16(a.y) << 16);
  u32 w1 = rne_bf16(a.z) | ((u32)rne_bf16(a.w) << 16);
  u32 w2 = rne_bf16(b.x) | ((u32)rne_bf16(b.y) << 16);
  u32 w3 = rne_bf16(b.z) | ((u32)rne_bf16(b.w) << 16);
  reinterpret_cast<uint4*>(xb)[i] = make_uint4(w0, w1, w2, w3);
}

// ================= W[k][c] (f32) -> Wt[c][k] (bf16), 6 matrices =================
__global__ __launch_bounds__(256) void k_prep_wt(const float* __restrict__ W_rel,
                                                 const float* __restrict__ W_root,
                                                 u16* __restrict__ Wt) {
  int id = blockIdx.x * 256 + threadIdx.x;
  if (id >= 6 * D * D) return;
  int col = id & 127;
  int k = (id >> 7) & 127;
  int m = id >> 14;
  const float* src = (m < 3) ? (W_rel + (size_t)m * D * D) : (W_root + (size_t)(m - 3) * D * D);
  Wt[(size_t)m * D * D + col * D + k] = rne_bf16(src[k * D + col]);
}

// ================= edge binning into 128-node buckets (validated) =================
__global__ __launch_bounds__(256) void k_bin(
    const int* __restrict__ src, const int* __restrict__ dst,
    int* __restrict__ gcnt, u32* __restrict__ ebuf, int n_edges, int nb) {
  __shared__ int lh[NB];
  int tid = threadIdx.x;
  int e0 = blockIdx.x * EPB;
  for (int b = tid; b < NB; b += 256) lh[b] = 0;
  __syncthreads();
  for (int i = tid; i < EPB; i += 256) {
    int e = e0 + i;
    if (e < n_edges) atomicAdd(&lh[dst[e] >> 7], 1);
  }
  __syncthreads();
  for (int b = tid; b < nb; b += 256) {
    int c = lh[b];
    lh[b] = (c > 0) ? (b * CAP + atomicAdd(&gcnt[b], c)) : 0;
  }
  __syncthreads();
  for (int i = tid; i < EPB; i += 256) {
    int e = e0 + i;
    if (e < n_edges) {
      int d = dst[e];
      int slot = atomicAdd(&lh[d >> 7], 1);
      ebuf[slot] = ((u32)(d & 127) << 20) | (u32)src[e];
    }
  }
}

// ================= per-bucket sort -> exact CSR (validated) =================
__global__ __launch_bounds__(256) void k_sort(
    const u32* __restrict__ ebuf, const int* __restrict__ gcnt,
    u32* __restrict__ eidx, int* __restrict__ rowptr, int* __restrict__ deg,
    int n_nodes) {
  __shared__ u32 earr[CAP];
  __shared__ int lh[128], sc[128], lcur[128];
  int tid = threadIdx.x;
  int b = blockIdx.x;
  int cnt = gcnt[b];
  int base = b * CAP;
  for (int i = tid; i < cnt; i += 256) earr[i] = ebuf[base + i];
  if (tid < 128) lh[tid] = 0;
  __syncthreads();
  for (int i = tid; i < cnt; i += 256) atomicAdd(&lh[earr[i] >> 20], 1);
  __syncthreads();
  if (tid < 128) sc[tid] = lh[tid];
  __syncthreads();
  #pragma unroll
  for (int off = 1; off < 128; off <<= 1) {
    int v = (tid < 128 && tid >= off) ? sc[tid - off] : 0;
    __syncthreads();
    if (tid < 128) sc[tid] += v;
    __syncthreads();
  }
  if (tid < 128) {
    int excl = sc[tid] - lh[tid];
    int n = b * 128 + tid;
    if (n < n_nodes) { rowptr[n] = base + excl; deg[n] = lh[tid]; }
    lcur[tid] = excl;
  }
  __syncthreads();
  for (int i = tid; i < cnt; i += 256) {
    u32 e = earr[i];
    int slot = atomicAdd(&lcur[e >> 20], 1);
    eidx[base + slot] = e & 0xFFFFF;
  }
}

// ================= gather (bf16, per-node, 4x unrolled for MLP) =================
__global__ __launch_bounds__(256) void k_gather(
    const u16* __restrict__ xb, const int* __restrict__ rowptr,
    const int* __restrict__ deg, const u32* __restrict__ eidx,
    u16* __restrict__ aggb, int n_nodes) {
  int tid = threadIdx.x;
  int n = blockIdx.x * 16 + (tid >> 4);
  int c = tid & 15;                        // 16B chunk (8 bf16) within the 256B row
  if (n >= n_nodes) return;
  int beg = rowptr[n];
  int dn = deg[n];
  float a0 = 0, a1 = 0, a2 = 0, a3 = 0, a4 = 0, a5 = 0, a6 = 0, a7 = 0;
  int i = 0;
  for (; i + 4 <= dn; i += 4) {            // 4 independent row loads in flight
    int s0 = (int)eidx[beg + i];
    int s1 = (int)eidx[beg + i + 1];
    int s2 = (int)eidx[beg + i + 2];
    int s3 = (int)eidx[beg + i + 3];
    uint4 v0 = *(reinterpret_cast<const uint4*>(xb + (size_t)s0 * D) + c);
    uint4 v1 = *(reinterpret_cast<const uint4*>(xb + (size_t)s1 * D) + c);
    uint4 v2 = *(reinterpret_cast<const uint4*>(xb + (size_t)s2 * D) + c);
    uint4 v3 = *(reinterpret_cast<const uint4*>(xb + (size_t)s3 * D) + c);
    a0 += bf_lo(v0.x) + bf_lo(v1.x) + bf_lo(v2.x) + bf_lo(v3.x);
    a1 += bf_hi(v0.x) + bf_hi(v1.x) + bf_hi(v2.x) + bf_hi(v3.x);
    a2 += bf_lo(v0.y) + bf_lo(v1.y) + bf_lo(v2.y) + bf_lo(v3.y);
    a3 += bf_hi(v0.y) + bf_hi(v1.y) + bf_hi(v2.y) + bf_hi(v3.y);
    a4 += bf_lo(v0.z) + bf_lo(v1.z) + bf_lo(v2.z) + bf_lo(v3.z);
    a5 += bf_hi(v0.z) + bf_hi(v1.z) + bf_hi(v2.z) + bf_hi(v3.z);
    a6 += bf_lo(v0.w) + bf_lo(v1.w) + bf_lo(v2.w) + bf_lo(v3.w);
    a7 += bf_hi(v0.w) + bf_hi(v1.w) + bf_hi(v2.w) + bf_hi(v3.w);
  }
  for (; i < dn; i++) {
    int s = (int)eidx[beg + i];
    uint4 v = *(reinterpret_cast<const uint4*>(xb + (size_t)s * D) + c);
    a0 += bf_lo(v.x); a1 += bf_hi(v.x);
    a2 += bf_lo(v.y); a3 += bf_hi(v.y);
    a4 += bf_lo(v.z); a5 += bf_hi(v.z);
    a6 += bf_lo(v.w); a7 += bf_hi(v.w);
  }
  u32 w0 = rne_bf16(a0) | ((u32)rne_bf16(a1) << 16);
  u32 w1 = rne_bf16(a2) | ((u32)rne_bf16(a3) << 16);
  u32 w2 = rne_bf16(a4) | ((u32)rne_bf16(a5) << 16);
  u32 w3 = rne_bf16(a6) | ((u32)rne_bf16(a7) << 16);
  *(reinterpret_cast<uint4*>(aggb + (size_t)n * D) + c) = make_uint4(w0, w1, w2, w3);
}

// ================= MFMA dual GEMM, async-staged + double-buffered =================
// LDS image identical to round-5 validated layout: stored[row][cb] = global[row][cb ^ ((row&7)<<4)]
// achieved via global_load_lds with inverse-swizzled SOURCE chunk (linear LDS dest).
__global__ __launch_bounds__(256) void k_gemm_mfma(
    const u16* __restrict__ A1, const u16* __restrict__ A2,
    const u16* __restrict__ Wt1, const u16* __restrict__ Wt2,
    const float* __restrict__ bias, u16* __restrict__ outp, int M) {
  __shared__ __align__(16) u16 As[2][128 * 64];
  __shared__ __align__(16) u16 Ws[2][128 * 64];
  int tid = threadIdx.x;
  int wave = tid >> 6, lane = tid & 63;
  int g = lane >> 4, lr = lane & 15;
  int r0 = blockIdx.x * 128;
  int wr = wave * 32;

  f32x4 acc[2][8];
  #pragma unroll
  for (int fr = 0; fr < 2; fr++)
    #pragma unroll
    for (int fc = 0; fc < 8; fc++)
      acc[fr][fc] = (f32x4){0.f, 0.f, 0.f, 0.f};

  const u16* Am[2] = {A1, A2};
  const u16* Wm[2] = {Wt1, Wt2};

  // stage one (pass, kh) tile pair into buffer buf: 8 x global_load_lds per thread
  auto STAGE = [&](int buf, const u16* A, const u16* Wt, int kh) {
    #pragma unroll
    for (int i = 0; i < 4; i++) {
      int gI = i * 256 + tid;                 // 0..1023
      int row = gI >> 3;                      // 0..127
      int cs = (gI & 7) ^ (row & 7);          // inverse-swizzled source chunk
      int rg = r0 + row; if (rg >= M) rg = M - 1;
      u16* la = &As[buf][(size_t)(i * 256 + wave * 64) * 8];   // wave-uniform
      gload_lds16(A + (size_t)rg * D + kh * 64 + cs * 8, la);
      u16* lw = &Ws[buf][(size_t)(i * 256 + wave * 64) * 8];
      gload_lds16(Wt + (size_t)row * D + kh * 64 + cs * 8, lw);
    }
  };

  STAGE(0, A1, Wt1, 0);
  __syncthreads();

  #pragma unroll 1
  for (int s = 0; s < 4; s++) {              // s = pass*2 + kh
    if (s < 3) {
      int ns = s + 1;
      STAGE(ns & 1, Am[ns >> 1], Wm[ns >> 1], ns & 1);   // prefetch in flight during MFMA
    }
    int buf = s & 1;
    #pragma unroll
    for (int kc = 0; kc < 2; kc++) {
      int kbyte = kc * 64 + g * 16;
      bf16x8 af[2];
      #pragma unroll
      for (int fr = 0; fr < 2; fr++) {
        int row = wr + fr * 16 + lr;
        int ob = (kbyte ^ ((row & 7) << 4)) >> 1;
        af[fr] = *reinterpret_cast<const bf16x8*>(&As[buf][row * 64 + ob]);
      }
      #pragma unroll
      for (int fc = 0; fc < 8; fc++) {
        int colw = fc * 16 + lr;
        int ob = (kbyte ^ ((colw & 7) << 4)) >> 1;
        bf16x8 bfv = *reinterpret_cast<const bf16x8*>(&Ws[buf][colw * 64 + ob]);
        #pragma unroll
        for (int fr = 0; fr < 2; fr++)
          acc[fr][fc] = __builtin_amdgcn_mfma_f32_16x16x32_bf16(
              af[fr], bfv, acc[fr][fc], 0, 0, 0);
      }
    }
    __syncthreads();   // drains this iter's prefetch (vmcnt) + guards buffer reuse
  }

  #pragma unroll
  for (int fc = 0; fc < 8; fc++) {
    float bc = bias[fc * 16 + lr];
    #pragma unroll
    for (int fr = 0; fr < 2; fr++) {
      #pragma unroll
      for (int j = 0; j < 4; j++) {
        int R = r0 + wr + fr * 16 + g * 4 + j;
        if (R < M)
          outp[(size_t)R * D + fc * 16 + lr] = rne_bf16(acc[fr][fc][j] + bc);
      }
    }
  }
}

// ================= mean pool (batch sorted, bf16 input) =================
#define CHUNK 256
__global__ __launch_bounds__(256) void k_pool(
    const u16* __restrict__ xb, const int* __restrict__ batch,
    float* __restrict__ pooled, int n_nodes) {
  int col = threadIdx.x & 127;
  int sub = threadIdx.x >> 7;
  int n0 = blockIdx.x * CHUNK;
  int nend = min(n0 + CHUNK, n_nodes);
  float sum = 0.f; int cur = -1;
  for (int n = n0 + sub; n < nend; n += 2) {
    int g = batch[n];
    if (g != cur) {
      if (cur >= 0) atomicAdd(&pooled[cur * D + col], sum);
      sum = 0.f; cur = g;
    }
    sum += __uint_as_float((u32)xb[(size_t)n * D + col] << 16);
  }
  if (cur >= 0) atomicAdd(&pooled[cur * D + col], sum);
}

// ================= graph start markers (batch sorted) =================
__global__ __launch_bounds__(256) void k_bounds(
    const int* __restrict__ batch, int* __restrict__ start, int n) {
  int i = blockIdx.x * 256 + threadIdx.x;
  if (i >= n) return;
  int g = batch[i];
  if (i == 0 || batch[i - 1] != g) start[g] = i;
}

// ================= head (computes counts from start markers) =================
__global__ void k_head(const float* __restrict__ pooled, const int* __restrict__ gstart,
                       const float* __restrict__ W_fc, const float* __restrict__ b_fc,
                       float* __restrict__ outp, int n_nodes) {
  int g = threadIdx.x;
  if (g >= NGRAPHS) return;
  int s = gstart[g];
  int c = 0;
  if (s >= 0) {
    int e = n_nodes;
    for (int h = g + 1; h < NGRAPHS; h++)
      if (gstart[h] >= 0) { e = gstart[h]; break; }
    c = e - s;
  }
  float inv = 1.0f / fmaxf((float)c, 1.0f);
  float logits[NCLASSES];
  #pragma unroll
  for (int j = 0; j < NCLASSES; j++) logits[j] = b_fc[j];
  for (int k = 0; k < D; k++) {
    float p = pooled[g * D + k] * inv;
    #pragma unroll
    for (int j = 0; j < NCLASSES; j++) logits[j] += p * W_fc[k * NCLASSES + j];
  }
  float m = logits[0];
  #pragma unroll
  for (int j = 1; j < NCLASSES; j++) m = fmaxf(m, logits[j]);
  float s2 = 0.f;
  #pragma unroll
  for (int j = 0; j < NCLASSES; j++) s2 += expf(logits[j] - m);
  float lse = m + logf(s2);
  #pragma unroll
  for (int j = 0; j < NCLASSES; j++) outp[g * NCLASSES + j] = logits[j] - lse;
}

extern "C" void kernel_launch(void* const* d_in, const int* in_sizes, int n_in,
                              void* d_out, int out_size, void* d_ws, size_t ws_size,
                              hipStream_t stream) {
  const float* x      = (const float*)d_in[0];
  const int*   ei     = (const int*)d_in[1];
  const int*   batch  = (const int*)d_in[2];
  const float* W_rel  = (const float*)d_in[3];
  const float* W_root = (const float*)d_in[4];
  const float* b_rel  = (const float*)d_in[5];
  const float* W_fc   = (const float*)d_in[6];
  const float* b_fc   = (const float*)d_in[7];
  float* outp = (float*)d_out;

  int n_nodes = in_sizes[0] / D;
  int n_edges = in_sizes[1] / 2;
  const int* src = ei;
  const int* dst = ei + n_edges;
  int nb = (n_nodes + 127) / 128;   // 782

  char* ws = (char*)d_ws;
  size_t bb = (size_t)n_nodes * D * sizeof(u16);   // 25.6 MB
  size_t nbts = (size_t)n_nodes * sizeof(int);
  u16* aggb   = (u16*)(ws);
  u16* xba    = (u16*)(ws + bb);
  u16* xbb    = (u16*)(ws + 2 * bb);
  char* p     = ws + 3 * bb;
  u16* Wt     = (u16*)(p);               p += (size_t)6 * D * D * sizeof(u16);
  int* gcnt   = (int*)(p);               p += (size_t)NB * sizeof(int);
  u32* ebuf   = (u32*)(p);               p += (size_t)NB * CAP * sizeof(u32);
  u32* eidx   = (u32*)(p);               p += (size_t)NB * CAP * sizeof(u32);
  int* rowptr = (int*)(p);               p += nbts;
  int* deg    = (int*)(p);               p += nbts;
  float* pooled = (float*)(p);           p += (size_t)NGRAPHS * D * sizeof(float);
  int* gstart = (int*)(p);

  // prep: weight transpose+cast, x cast, bucket binning + per-bucket CSR sort
  k_prep_wt<<<(6 * D * D + 255) / 256, 256, 0, stream>>>(W_rel, W_root, Wt);
  long long n8 = (long long)n_nodes * D / 8;
  k_cast0<<<(int)((n8 + 255) / 256), 256, 0, stream>>>(x, xba, n8);
  hipMemsetAsync(gcnt, 0, (size_t)NB * sizeof(int), stream);
  k_bin<<<(n_edges + EPB - 1) / EPB, 256, 0, stream>>>(src, dst, gcnt, ebuf, n_edges, nb);
  k_sort<<<nb, 256, 0, stream>>>(ebuf, gcnt, eidx, rowptr, deg, n_nodes);

  // 3 GraphConv layers
  u16* xc = xba;
  u16* xn = xbb;
  int gemmblk = (n_nodes + 127) / 128;
  for (int l = 0; l < 3; l++) {
    k_gather<<<(n_nodes + 15) / 16, 256, 0, stream>>>(xc, rowptr, deg, eidx, aggb, n_nodes);
    k_gemm_mfma<<<gemmblk, 256, 0, stream>>>(
        aggb, xc, Wt + (size_t)l * D * D, Wt + (size_t)(3 + l) * D * D,
        b_rel + (size_t)l * D, xn, n_nodes);
    u16* t = xc; xc = xn; xn = t;
  }

  // pool + head
  hipMemsetAsync(pooled, 0, (size_t)NGRAPHS * D * sizeof(float), stream);
  hipMemsetAsync(gstart, 0xFF, (size_t)NGRAPHS * sizeof(int), stream);
  k_pool<<<(n_nodes + CHUNK - 1) / CHUNK, 256, 0, stream>>>(xc, batch, pooled, n_nodes);
  k_bounds<<<(n_nodes + 255) / 256, 256, 0, stream>>>(batch, gstart, n_nodes);
  k_head<<<1, 64, 0, stream>>>(pooled, gstart, W_fc, b_fc, outp, n_nodes);
}

// Round 10
// 486.172 us; speedup vs baseline: 8.8521x; 1.0230x over previous
//
#include <hip/hip_runtime.h>
#include <hip/hip_bf16.h>

#define D 128
#define NGRAPHS 64
#define NCLASSES 10
#define NB 800        // bucket array size (ceil(100000/128)=782, padded)
#define CAP 3072      // max edges per bucket (mean 2048, sigma~45 -> 22 sigma)
#define EPB 8192      // edges per k_bin block

typedef unsigned short u16;
typedef unsigned int u32;
typedef __attribute__((ext_vector_type(8))) short bf16x8;
typedef __attribute__((ext_vector_type(4))) float f32x4;

__device__ __forceinline__ u16 rne_bf16(float f) {
  u32 u = __float_as_uint(f);
  u += 0x7FFFu + ((u >> 16) & 1u);
  return (u16)(u >> 16);
}
__device__ __forceinline__ float bf_lo(u32 u) { return __uint_as_float(u << 16); }
__device__ __forceinline__ float bf_hi(u32 u) { return __uint_as_float(u & 0xFFFF0000u); }

// async global->LDS, 16B per lane, dest = wave-uniform base + lane*16
__device__ __forceinline__ void gload_lds16(const void* g, void* l) {
  __builtin_amdgcn_global_load_lds(
      (const __attribute__((address_space(1))) void*)g,
      (__attribute__((address_space(3))) void*)l, 16, 0, 0);
}

// ================= f32 -> bf16 cast of x =================
__global__ __launch_bounds__(256) void k_cast0(const float* __restrict__ x,
                                               u16* __restrict__ xb, long long n8) {
  long long i = (long long)blockIdx.x * 256 + threadIdx.x;
  if (i >= n8) return;
  const float4* xp = reinterpret_cast<const float4*>(x) + i * 2;
  float4 a = xp[0], b = xp[1];
  u32 w0 = rne_bf16(a.x) | ((u32)rne_bf16(a.y) << 16);
  u32 w1 = rne_bf16(a.z) | ((u32)rne_bf16(a.w) << 16);
  u32 w2 = rne_bf16(b.x) | ((u32)rne_bf16(b.y) << 16);
  u32 w3 = rne_bf16(b.z) | ((u32)rne_bf16(b.w) << 16);
  reinterpret_cast<uint4*>(xb)[i] = make_uint4(w0, w1, w2, w3);
}

// ================= W[k][c] (f32) -> Wt[c][k] (bf16), 6 matrices =================
__global__ __launch_bounds__(256) void k_prep_wt(const float* __restrict__ W_rel,
                                                 const float* __restrict__ W_root,
                                                 u16* __restrict__ Wt) {
  int id = blockIdx.x * 256 + threadIdx.x;
  if (id >= 6 * D * D) return;
  int col = id & 127;
  int k = (id >> 7) & 127;
  int m = id >> 14;
  const float* src = (m < 3) ? (W_rel + (size_t)m * D * D) : (W_root + (size_t)(m - 3) * D * D);
  Wt[(size_t)m * D * D + col * D + k] = rne_bf16(src[k * D + col]);
}

// ================= edge binning into 128-node buckets (validated) =================
__global__ __launch_bounds__(256) void k_bin(
    const int* __restrict__ src, const int* __restrict__ dst,
    int* __restrict__ gcnt, u32* __restrict__ ebuf, int n_edges, int nb) {
  __shared__ int lh[NB];
  int tid = threadIdx.x;
  int e0 = blockIdx.x * EPB;
  for (int b = tid; b < NB; b += 256) lh[b] = 0;
  __syncthreads();
  for (int i = tid; i < EPB; i += 256) {
    int e = e0 + i;
    if (e < n_edges) atomicAdd(&lh[dst[e] >> 7], 1);
  }
  __syncthreads();
  for (int b = tid; b < nb; b += 256) {
    int c = lh[b];
    lh[b] = (c > 0) ? (b * CAP + atomicAdd(&gcnt[b], c)) : 0;
  }
  __syncthreads();
  for (int i = tid; i < EPB; i += 256) {
    int e = e0 + i;
    if (e < n_edges) {
      int d = dst[e];
      int slot = atomicAdd(&lh[d >> 7], 1);
      ebuf[slot] = ((u32)(d & 127) << 20) | (u32)src[e];
    }
  }
}

// ================= per-bucket sort -> exact CSR (validated) =================
__global__ __launch_bounds__(256) void k_sort(
    const u32* __restrict__ ebuf, const int* __restrict__ gcnt,
    u32* __restrict__ eidx, int* __restrict__ rowptr, int* __restrict__ deg,
    int n_nodes) {
  __shared__ u32 earr[CAP];
  __shared__ int lh[128], sc[128], lcur[128];
  int tid = threadIdx.x;
  int b = blockIdx.x;
  int cnt = gcnt[b];
  int base = b * CAP;
  for (int i = tid; i < cnt; i += 256) earr[i] = ebuf[base + i];
  if (tid < 128) lh[tid] = 0;
  __syncthreads();
  for (int i = tid; i < cnt; i += 256) atomicAdd(&lh[earr[i] >> 20], 1);
  __syncthreads();
  if (tid < 128) sc[tid] = lh[tid];
  __syncthreads();
  #pragma unroll
  for (int off = 1; off < 128; off <<= 1) {
    int v = (tid < 128 && tid >= off) ? sc[tid - off] : 0;
    __syncthreads();
    if (tid < 128) sc[tid] += v;
    __syncthreads();
  }
  if (tid < 128) {
    int excl = sc[tid] - lh[tid];
    int n = b * 128 + tid;
    if (n < n_nodes) { rowptr[n] = base + excl; deg[n] = lh[tid]; }
    lcur[tid] = excl;
  }
  __syncthreads();
  for (int i = tid; i < cnt; i += 256) {
    u32 e = earr[i];
    int slot = atomicAdd(&lcur[e >> 20], 1);
    eidx[base + slot] = e & 0xFFFFF;
  }
}

// ================= gather: ONE WAVE PER NODE =================
// lane = (edge-slot es 0..3, chunk c 0..15). Per iter: 1 broadcast eidx dword +
// 1 coalesced 1KB row load covers 4 edges (vs 8 vmem instrs before). No
// intra-wave degree divergence. Epilogue: shfl_xor(16/32) reduce, lanes 0-15 store.
__global__ __launch_bounds__(256) void k_gather(
    const u16* __restrict__ xb, const int* __restrict__ rowptr,
    const int* __restrict__ deg, const u32* __restrict__ eidx,
    u16* __restrict__ aggb, int n_nodes) {
  int tid = threadIdx.x;
  int lane = tid & 63;
  int n = blockIdx.x * 4 + (tid >> 6);
  if (n >= n_nodes) return;
  int es = lane >> 4;            // edge slot within group of 4
  int c = lane & 15;             // 16B chunk within 256B row
  int beg = rowptr[n];
  int dn = deg[n];
  float a0 = 0, a1 = 0, a2 = 0, a3 = 0, a4 = 0, a5 = 0, a6 = 0, a7 = 0;
  int i = 0;
  for (; i + 8 <= dn; i += 8) {  // 8 edges in flight (2 row loads + 2 eidx)
    int s0 = (int)eidx[beg + i + es];
    int s1 = (int)eidx[beg + i + 4 + es];
    uint4 v0 = *(reinterpret_cast<const uint4*>(xb + (size_t)s0 * D) + c);
    uint4 v1 = *(reinterpret_cast<const uint4*>(xb + (size_t)s1 * D) + c);
    a0 += bf_lo(v0.x) + bf_lo(v1.x); a1 += bf_hi(v0.x) + bf_hi(v1.x);
    a2 += bf_lo(v0.y) + bf_lo(v1.y); a3 += bf_hi(v0.y) + bf_hi(v1.y);
    a4 += bf_lo(v0.z) + bf_lo(v1.z); a5 += bf_hi(v0.z) + bf_hi(v1.z);
    a6 += bf_lo(v0.w) + bf_lo(v1.w); a7 += bf_hi(v0.w) + bf_hi(v1.w);
  }
  for (; i < dn; i += 4) {       // predicated tail, <=2 iters
    bool p = (i + es) < dn;
    int s = p ? (int)eidx[beg + i + es] : 0;
    if (p) {
      uint4 v = *(reinterpret_cast<const uint4*>(xb + (size_t)s * D) + c);
      a0 += bf_lo(v.x); a1 += bf_hi(v.x);
      a2 += bf_lo(v.y); a3 += bf_hi(v.y);
      a4 += bf_lo(v.z); a5 += bf_hi(v.z);
      a6 += bf_lo(v.w); a7 += bf_hi(v.w);
    }
  }
  // cross-lane reduce over the 4 edge-slots (lanes c, c+16, c+32, c+48)
  #pragma unroll
  for (int d = 16; d <= 32; d <<= 1) {
    a0 += __shfl_xor(a0, d); a1 += __shfl_xor(a1, d);
    a2 += __shfl_xor(a2, d); a3 += __shfl_xor(a3, d);
    a4 += __shfl_xor(a4, d); a5 += __shfl_xor(a5, d);
    a6 += __shfl_xor(a6, d); a7 += __shfl_xor(a7, d);
  }
  if (es == 0) {
    u32 w0 = rne_bf16(a0) | ((u32)rne_bf16(a1) << 16);
    u32 w1 = rne_bf16(a2) | ((u32)rne_bf16(a3) << 16);
    u32 w2 = rne_bf16(a4) | ((u32)rne_bf16(a5) << 16);
    u32 w3 = rne_bf16(a6) | ((u32)rne_bf16(a7) << 16);
    *(reinterpret_cast<uint4*>(aggb + (size_t)n * D) + c) = make_uint4(w0, w1, w2, w3);
  }
}

// ================= MFMA dual GEMM, async-staged + double-buffered =================
__global__ __launch_bounds__(256) void k_gemm_mfma(
    const u16* __restrict__ A1, const u16* __restrict__ A2,
    const u16* __restrict__ Wt1, const u16* __restrict__ Wt2,
    const float* __restrict__ bias, u16* __restrict__ outp, int M) {
  __shared__ __align__(16) u16 As[2][128 * 64];
  __shared__ __align__(16) u16 Ws[2][128 * 64];
  int tid = threadIdx.x;
  int wave = tid >> 6, lane = tid & 63;
  int g = lane >> 4, lr = lane & 15;
  int r0 = blockIdx.x * 128;
  int wr = wave * 32;

  f32x4 acc[2][8];
  #pragma unroll
  for (int fr = 0; fr < 2; fr++)
    #pragma unroll
    for (int fc = 0; fc < 8; fc++)
      acc[fr][fc] = (f32x4){0.f, 0.f, 0.f, 0.f};

  const u16* Am[2] = {A1, A2};
  const u16* Wm[2] = {Wt1, Wt2};

  auto STAGE = [&](int buf, const u16* A, const u16* Wt, int kh) {
    #pragma unroll
    for (int i = 0; i < 4; i++) {
      int gI = i * 256 + tid;                 // 0..1023
      int row = gI >> 3;                      // 0..127
      int cs = (gI & 7) ^ (row & 7);          // inverse-swizzled source chunk
      int rg = r0 + row; if (rg >= M) rg = M - 1;
      u16* la = &As[buf][(size_t)(i * 256 + wave * 64) * 8];   // wave-uniform
      gload_lds16(A + (size_t)rg * D + kh * 64 + cs * 8, la);
      u16* lw = &Ws[buf][(size_t)(i * 256 + wave * 64) * 8];
      gload_lds16(Wt + (size_t)row * D + kh * 64 + cs * 8, lw);
    }
  };

  STAGE(0, A1, Wt1, 0);
  __syncthreads();

  #pragma unroll 1
  for (int s = 0; s < 4; s++) {              // s = pass*2 + kh
    if (s < 3) {
      int ns = s + 1;
      STAGE(ns & 1, Am[ns >> 1], Wm[ns >> 1], ns & 1);
    }
    int buf = s & 1;
    #pragma unroll
    for (int kc = 0; kc < 2; kc++) {
      int kbyte = kc * 64 + g * 16;
      bf16x8 af[2];
      #pragma unroll
      for (int fr = 0; fr < 2; fr++) {
        int row = wr + fr * 16 + lr;
        int ob = (kbyte ^ ((row & 7) << 4)) >> 1;
        af[fr] = *reinterpret_cast<const bf16x8*>(&As[buf][row * 64 + ob]);
      }
      #pragma unroll
      for (int fc = 0; fc < 8; fc++) {
        int colw = fc * 16 + lr;
        int ob = (kbyte ^ ((colw & 7) << 4)) >> 1;
        bf16x8 bfv = *reinterpret_cast<const bf16x8*>(&Ws[buf][colw * 64 + ob]);
        #pragma unroll
        for (int fr = 0; fr < 2; fr++)
          acc[fr][fc] = __builtin_amdgcn_mfma_f32_16x16x32_bf16(
              af[fr], bfv, acc[fr][fc], 0, 0, 0);
      }
    }
    __syncthreads();
  }

  #pragma unroll
  for (int fc = 0; fc < 8; fc++) {
    float bc = bias[fc * 16 + lr];
    #pragma unroll
    for (int fr = 0; fr < 2; fr++) {
      #pragma unroll
      for (int j = 0; j < 4; j++) {
        int R = r0 + wr + fr * 16 + g * 4 + j;
        if (R < M)
          outp[(size_t)R * D + fc * 16 + lr] = rne_bf16(acc[fr][fc][j] + bc);
      }
    }
  }
}

// ================= mean pool (batch sorted, bf16 input) =================
#define CHUNK 256
__global__ __launch_bounds__(256) void k_pool(
    const u16* __restrict__ xb, const int* __restrict__ batch,
    float* __restrict__ pooled, int n_nodes) {
  int col = threadIdx.x & 127;
  int sub = threadIdx.x >> 7;
  int n0 = blockIdx.x * CHUNK;
  int nend = min(n0 + CHUNK, n_nodes);
  float sum = 0.f; int cur = -1;
  for (int n = n0 + sub; n < nend; n += 2) {
    int g = batch[n];
    if (g != cur) {
      if (cur >= 0) atomicAdd(&pooled[cur * D + col], sum);
      sum = 0.f; cur = g;
    }
    sum += __uint_as_float((u32)xb[(size_t)n * D + col] << 16);
  }
  if (cur >= 0) atomicAdd(&pooled[cur * D + col], sum);
}

// ================= graph start markers (batch sorted) =================
__global__ __launch_bounds__(256) void k_bounds(
    const int* __restrict__ batch, int* __restrict__ start, int n) {
  int i = blockIdx.x * 256 + threadIdx.x;
  if (i >= n) return;
  int g = batch[i];
  if (i == 0 || batch[i - 1] != g) start[g] = i;
}

// ================= head (computes counts from start markers) =================
__global__ void k_head(const float* __restrict__ pooled, const int* __restrict__ gstart,
                       const float* __restrict__ W_fc, const float* __restrict__ b_fc,
                       float* __restrict__ outp, int n_nodes) {
  int g = threadIdx.x;
  if (g >= NGRAPHS) return;
  int s = gstart[g];
  int c = 0;
  if (s >= 0) {
    int e = n_nodes;
    for (int h = g + 1; h < NGRAPHS; h++)
      if (gstart[h] >= 0) { e = gstart[h]; break; }
    c = e - s;
  }
  float inv = 1.0f / fmaxf((float)c, 1.0f);
  float logits[NCLASSES];
  #pragma unroll
  for (int j = 0; j < NCLASSES; j++) logits[j] = b_fc[j];
  for (int k = 0; k < D; k++) {
    float p = pooled[g * D + k] * inv;
    #pragma unroll
    for (int j = 0; j < NCLASSES; j++) logits[j] += p * W_fc[k * NCLASSES + j];
  }
  float m = logits[0];
  #pragma unroll
  for (int j = 1; j < NCLASSES; j++) m = fmaxf(m, logits[j]);
  float s2 = 0.f;
  #pragma unroll
  for (int j = 0; j < NCLASSES; j++) s2 += expf(logits[j] - m);
  float lse = m + logf(s2);
  #pragma unroll
  for (int j = 0; j < NCLASSES; j++) outp[g * NCLASSES + j] = logits[j] - lse;
}

extern "C" void kernel_launch(void* const* d_in, const int* in_sizes, int n_in,
                              void* d_out, int out_size, void* d_ws, size_t ws_size,
                              hipStream_t stream) {
  const float* x      = (const float*)d_in[0];
  const int*   ei     = (const int*)d_in[1];
  const int*   batch  = (const int*)d_in[2];
  const float* W_rel  = (const float*)d_in[3];
  const float* W_root = (const float*)d_in[4];
  const float* b_rel  = (const float*)d_in[5];
  const float* W_fc   = (const float*)d_in[6];
  const float* b_fc   = (const float*)d_in[7];
  float* outp = (float*)d_out;

  int n_nodes = in_sizes[0] / D;
  int n_edges = in_sizes[1] / 2;
  const int* src = ei;
  const int* dst = ei + n_edges;
  int nb = (n_nodes + 127) / 128;   // 782

  char* ws = (char*)d_ws;
  size_t bb = (size_t)n_nodes * D * sizeof(u16);   // 25.6 MB
  size_t nbts = (size_t)n_nodes * sizeof(int);
  u16* aggb   = (u16*)(ws);
  u16* xba    = (u16*)(ws + bb);
  u16* xbb    = (u16*)(ws + 2 * bb);
  char* p     = ws + 3 * bb;
  u16* Wt     = (u16*)(p);               p += (size_t)6 * D * D * sizeof(u16);
  int* gcnt   = (int*)(p);               p += (size_t)NB * sizeof(int);
  u32* ebuf   = (u32*)(p);               p += (size_t)NB * CAP * sizeof(u32);
  u32* eidx   = (u32*)(p);               p += (size_t)NB * CAP * sizeof(u32);
  int* rowptr = (int*)(p);               p += nbts;
  int* deg    = (int*)(p);               p += nbts;
  float* pooled = (float*)(p);           p += (size_t)NGRAPHS * D * sizeof(float);
  int* gstart = (int*)(p);

  // prep: weight transpose+cast, x cast, bucket binning + per-bucket CSR sort
  k_prep_wt<<<(6 * D * D + 255) / 256, 256, 0, stream>>>(W_rel, W_root, Wt);
  long long n8 = (long long)n_nodes * D / 8;
  k_cast0<<<(int)((n8 + 255) / 256), 256, 0, stream>>>(x, xba, n8);
  hipMemsetAsync(gcnt, 0, (size_t)NB * sizeof(int), stream);
  k_bin<<<(n_edges + EPB - 1) / EPB, 256, 0, stream>>>(src, dst, gcnt, ebuf, n_edges, nb);
  k_sort<<<nb, 256, 0, stream>>>(ebuf, gcnt, eidx, rowptr, deg, n_nodes);

  // 3 GraphConv layers
  u16* xc = xba;
  u16* xn = xbb;
  int gemmblk = (n_nodes + 127) / 128;
  for (int l = 0; l < 3; l++) {
    k_gather<<<(n_nodes + 3) / 4, 256, 0, stream>>>(xc, rowptr, deg, eidx, aggb, n_nodes);
    k_gemm_mfma<<<gemmblk, 256, 0, stream>>>(
        aggb, xc, Wt + (size_t)l * D * D, Wt + (size_t)(3 + l) * D * D,
        b_rel + (size_t)l * D, xn, n_nodes);
    u16* t = xc; xc = xn; xn = t;
  }

  // pool + head
  hipMemsetAsync(pooled, 0, (size_t)NGRAPHS * D * sizeof(float), stream);
  hipMemsetAsync(gstart, 0xFF, (size_t)NGRAPHS * sizeof(int), stream);
  k_pool<<<(n_nodes + CHUNK - 1) / CHUNK, 256, 0, stream>>>(xc, batch, pooled, n_nodes);
  k_bounds<<<(n_nodes + 255) / 256, 256, 0, stream>>>(batch, gstart, n_nodes);
  k_head<<<1, 64, 0, stream>>>(pooled, gstart, W_fc, b_fc, outp, n_nodes);
}

// Round 11
// 468.171 us; speedup vs baseline: 9.1924x; 1.0384x over previous
//
#include <hip/hip_runtime.h>
#include <hip/hip_bf16.h>

#define D 128
#define NGRAPHS 64
#define NCLASSES 10
#define NB 800        // bucket array size (ceil(100000/128)=782, padded)
#define CAP 3072      // max edges per bucket (mean 2048, sigma~45 -> 22 sigma)
#define EPB 8192      // edges per k_bin block

typedef unsigned short u16;
typedef unsigned int u32;
typedef __attribute__((ext_vector_type(8))) short bf16x8;
typedef __attribute__((ext_vector_type(4))) float f32x4;

__device__ __forceinline__ u16 rne_bf16(float f) {
  u32 u = __float_as_uint(f);
  u += 0x7FFFu + ((u >> 16) & 1u);
  return (u16)(u >> 16);
}
__device__ __forceinline__ float bf_lo(u32 u) { return __uint_as_float(u << 16); }
__device__ __forceinline__ float bf_hi(u32 u) { return __uint_as_float(u & 0xFFFF0000u); }

// async global->LDS, 16B per lane, dest = wave-uniform base + lane*16
__device__ __forceinline__ void gload_lds16(const void* g, void* l) {
  __builtin_amdgcn_global_load_lds(
      (const __attribute__((address_space(1))) void*)g,
      (__attribute__((address_space(3))) void*)l, 16, 0, 0);
}

// ================= f32 -> bf16 cast of x =================
__global__ __launch_bounds__(256) void k_cast0(const float* __restrict__ x,
                                               u16* __restrict__ xb, long long n8) {
  long long i = (long long)blockIdx.x * 256 + threadIdx.x;
  if (i >= n8) return;
  const float4* xp = reinterpret_cast<const float4*>(x) + i * 2;
  float4 a = xp[0], b = xp[1];
  u32 w0 = rne_bf16(a.x) | ((u32)rne_bf16(a.y) << 16);
  u32 w1 = rne_bf16(a.z) | ((u32)rne_bf16(a.w) << 16);
  u32 w2 = rne_bf16(b.x) | ((u32)rne_bf16(b.y) << 16);
  u32 w3 = rne_bf16(b.z) | ((u32)rne_bf16(b.w) << 16);
  reinterpret_cast<uint4*>(xb)[i] = make_uint4(w0, w1, w2, w3);
}

// ================= W[k][c] (f32) -> Wt[c][k] (bf16), 6 matrices =================
__global__ __launch_bounds__(256) void k_prep_wt(const float* __restrict__ W_rel,
                                                 const float* __restrict__ W_root,
                                                 u16* __restrict__ Wt) {
  int id = blockIdx.x * 256 + threadIdx.x;
  if (id >= 6 * D * D) return;
  int col = id & 127;
  int k = (id >> 7) & 127;
  int m = id >> 14;
  const float* src = (m < 3) ? (W_rel + (size_t)m * D * D) : (W_root + (size_t)(m - 3) * D * D);
  Wt[(size_t)m * D * D + col * D + k] = rne_bf16(src[k * D + col]);
}

// ================= edge binning into 128-node buckets (validated) =================
__global__ __launch_bounds__(256) void k_bin(
    const int* __restrict__ src, const int* __restrict__ dst,
    int* __restrict__ gcnt, u32* __restrict__ ebuf, int n_edges, int nb) {
  __shared__ int lh[NB];
  int tid = threadIdx.x;
  int e0 = blockIdx.x * EPB;
  for (int b = tid; b < NB; b += 256) lh[b] = 0;
  __syncthreads();
  for (int i = tid; i < EPB; i += 256) {
    int e = e0 + i;
    if (e < n_edges) atomicAdd(&lh[dst[e] >> 7], 1);
  }
  __syncthreads();
  for (int b = tid; b < nb; b += 256) {
    int c = lh[b];
    lh[b] = (c > 0) ? (b * CAP + atomicAdd(&gcnt[b], c)) : 0;
  }
  __syncthreads();
  for (int i = tid; i < EPB; i += 256) {
    int e = e0 + i;
    if (e < n_edges) {
      int d = dst[e];
      int slot = atomicAdd(&lh[d >> 7], 1);
      ebuf[slot] = ((u32)(d & 127) << 20) | (u32)src[e];
    }
  }
}

// ================= per-bucket sort -> exact CSR (validated) =================
__global__ __launch_bounds__(256) void k_sort(
    const u32* __restrict__ ebuf, const int* __restrict__ gcnt,
    u32* __restrict__ eidx, int* __restrict__ rowptr, int* __restrict__ deg,
    int n_nodes) {
  __shared__ u32 earr[CAP];
  __shared__ int lh[128], sc[128], lcur[128];
  int tid = threadIdx.x;
  int b = blockIdx.x;
  int cnt = gcnt[b];
  int base = b * CAP;
  for (int i = tid; i < cnt; i += 256) earr[i] = ebuf[base + i];
  if (tid < 128) lh[tid] = 0;
  __syncthreads();
  for (int i = tid; i < cnt; i += 256) atomicAdd(&lh[earr[i] >> 20], 1);
  __syncthreads();
  if (tid < 128) sc[tid] = lh[tid];
  __syncthreads();
  #pragma unroll
  for (int off = 1; off < 128; off <<= 1) {
    int v = (tid < 128 && tid >= off) ? sc[tid - off] : 0;
    __syncthreads();
    if (tid < 128) sc[tid] += v;
    __syncthreads();
  }
  if (tid < 128) {
    int excl = sc[tid] - lh[tid];
    int n = b * 128 + tid;
    if (n < n_nodes) { rowptr[n] = base + excl; deg[n] = lh[tid]; }
    lcur[tid] = excl;
  }
  __syncthreads();
  for (int i = tid; i < cnt; i += 256) {
    u32 e = earr[i];
    int slot = atomicAdd(&lcur[e >> 20], 1);
    eidx[base + slot] = e & 0xFFFFF;
  }
}

// ================= gather (at measured L3-path roofline, ~59us) =================
// 16 threads/node, unroll-4 and wave/node both land 58-59us with FETCH 178MB
// (< 8x25.6MB per-XCD lower bound) -> L2-miss-path BW floor. Keep round-8 form.
__global__ __launch_bounds__(256) void k_gather(
    const u16* __restrict__ xb, const int* __restrict__ rowptr,
    const int* __restrict__ deg, const u32* __restrict__ eidx,
    u16* __restrict__ aggb, int n_nodes) {
  int tid = threadIdx.x;
  int lane = tid & 63;
  int n = blockIdx.x * 4 + (tid >> 6);
  if (n >= n_nodes) return;
  int es = lane >> 4;            // edge slot within group of 4
  int c = lane & 15;             // 16B chunk within 256B row
  int beg = rowptr[n];
  int dn = deg[n];
  float a0 = 0, a1 = 0, a2 = 0, a3 = 0, a4 = 0, a5 = 0, a6 = 0, a7 = 0;
  int i = 0;
  for (; i + 8 <= dn; i += 8) {  // 8 edges in flight (2 row loads + 2 eidx)
    int s0 = (int)eidx[beg + i + es];
    int s1 = (int)eidx[beg + i + 4 + es];
    uint4 v0 = *(reinterpret_cast<const uint4*>(xb + (size_t)s0 * D) + c);
    uint4 v1 = *(reinterpret_cast<const uint4*>(xb + (size_t)s1 * D) + c);
    a0 += bf_lo(v0.x) + bf_lo(v1.x); a1 += bf_hi(v0.x) + bf_hi(v1.x);
    a2 += bf_lo(v0.y) + bf_lo(v1.y); a3 += bf_hi(v0.y) + bf_hi(v1.y);
    a4 += bf_lo(v0.z) + bf_lo(v1.z); a5 += bf_hi(v0.z) + bf_hi(v1.z);
    a6 += bf_lo(v0.w) + bf_lo(v1.w); a7 += bf_hi(v0.w) + bf_hi(v1.w);
  }
  for (; i < dn; i += 4) {       // predicated tail, <=2 iters
    bool p = (i + es) < dn;
    int s = p ? (int)eidx[beg + i + es] : 0;
    if (p) {
      uint4 v = *(reinterpret_cast<const uint4*>(xb + (size_t)s * D) + c);
      a0 += bf_lo(v.x); a1 += bf_hi(v.x);
      a2 += bf_lo(v.y); a3 += bf_hi(v.y);
      a4 += bf_lo(v.z); a5 += bf_hi(v.z);
      a6 += bf_lo(v.w); a7 += bf_hi(v.w);
    }
  }
  #pragma unroll
  for (int d = 16; d <= 32; d <<= 1) {
    a0 += __shfl_xor(a0, d); a1 += __shfl_xor(a1, d);
    a2 += __shfl_xor(a2, d); a3 += __shfl_xor(a3, d);
    a4 += __shfl_xor(a4, d); a5 += __shfl_xor(a5, d);
    a6 += __shfl_xor(a6, d); a7 += __shfl_xor(a7, d);
  }
  if (es == 0) {
    u32 w0 = rne_bf16(a0) | ((u32)rne_bf16(a1) << 16);
    u32 w1 = rne_bf16(a2) | ((u32)rne_bf16(a3) << 16);
    u32 w2 = rne_bf16(a4) | ((u32)rne_bf16(a5) << 16);
    u32 w3 = rne_bf16(a6) | ((u32)rne_bf16(a7) << 16);
    *(reinterpret_cast<uint4*>(aggb + (size_t)n * D) + c) = make_uint4(w0, w1, w2, w3);
  }
}

// ================= MFMA dual GEMM, async-staged + double-buffered =================
__global__ __launch_bounds__(256) void k_gemm_mfma(
    const u16* __restrict__ A1, const u16* __restrict__ A2,
    const u16* __restrict__ Wt1, const u16* __restrict__ Wt2,
    const float* __restrict__ bias, u16* __restrict__ outp, int M) {
  __shared__ __align__(16) u16 As[2][128 * 64];
  __shared__ __align__(16) u16 Ws[2][128 * 64];
  int tid = threadIdx.x;
  int wave = tid >> 6, lane = tid & 63;
  int g = lane >> 4, lr = lane & 15;
  int r0 = blockIdx.x * 128;
  int wr = wave * 32;

  f32x4 acc[2][8];
  #pragma unroll
  for (int fr = 0; fr < 2; fr++)
    #pragma unroll
    for (int fc = 0; fc < 8; fc++)
      acc[fr][fc] = (f32x4){0.f, 0.f, 0.f, 0.f};

  const u16* Am[2] = {A1, A2};
  const u16* Wm[2] = {Wt1, Wt2};

  auto STAGE = [&](int buf, const u16* A, const u16* Wt, int kh) {
    #pragma unroll
    for (int i = 0; i < 4; i++) {
      int gI = i * 256 + tid;                 // 0..1023
      int row = gI >> 3;                      // 0..127
      int cs = (gI & 7) ^ (row & 7);          // inverse-swizzled source chunk
      int rg = r0 + row; if (rg >= M) rg = M - 1;
      u16* la = &As[buf][(size_t)(i * 256 + wave * 64) * 8];   // wave-uniform
      gload_lds16(A + (size_t)rg * D + kh * 64 + cs * 8, la);
      u16* lw = &Ws[buf][(size_t)(i * 256 + wave * 64) * 8];
      gload_lds16(Wt + (size_t)row * D + kh * 64 + cs * 8, lw);
    }
  };

  STAGE(0, A1, Wt1, 0);
  __syncthreads();

  #pragma unroll 1
  for (int s = 0; s < 4; s++) {              // s = pass*2 + kh
    if (s < 3) {
      int ns = s + 1;
      STAGE(ns & 1, Am[ns >> 1], Wm[ns >> 1], ns & 1);
    }
    int buf = s & 1;
    #pragma unroll
    for (int kc = 0; kc < 2; kc++) {
      int kbyte = kc * 64 + g * 16;
      bf16x8 af[2];
      #pragma unroll
      for (int fr = 0; fr < 2; fr++) {
        int row = wr + fr * 16 + lr;
        int ob = (kbyte ^ ((row & 7) << 4)) >> 1;
        af[fr] = *reinterpret_cast<const bf16x8*>(&As[buf][row * 64 + ob]);
      }
      #pragma unroll
      for (int fc = 0; fc < 8; fc++) {
        int colw = fc * 16 + lr;
        int ob = (kbyte ^ ((colw & 7) << 4)) >> 1;
        bf16x8 bfv = *reinterpret_cast<const bf16x8*>(&Ws[buf][colw * 64 + ob]);
        #pragma unroll
        for (int fr = 0; fr < 2; fr++)
          acc[fr][fc] = __builtin_amdgcn_mfma_f32_16x16x32_bf16(
              af[fr], bfv, acc[fr][fc], 0, 0, 0);
      }
    }
    __syncthreads();
  }

  #pragma unroll
  for (int fc = 0; fc < 8; fc++) {
    float bc = bias[fc * 16 + lr];
    #pragma unroll
    for (int fr = 0; fr < 2; fr++) {
      #pragma unroll
      for (int j = 0; j < 4; j++) {
        int R = r0 + wr + fr * 16 + g * 4 + j;
        if (R < M)
          outp[(size_t)R * D + fc * 16 + lr] = rne_bf16(acc[fr][fc][j] + bc);
      }
    }
  }
}

// ================= fused pool + head: one block per graph (batch sorted) ==========
// Binary-search the graph's node range, accumulate in registers/LDS (no atomics,
// no memsets), then logits + log_softmax in-block. Replaces pool/bounds/head.
__global__ __launch_bounds__(256) void k_poolhead(
    const u16* __restrict__ xb, const int* __restrict__ batch,
    const float* __restrict__ W_fc, const float* __restrict__ b_fc,
    float* __restrict__ outp, int n_nodes) {
  __shared__ float pp[16][128];
  __shared__ float lg[128][NCLASSES];
  int tid = threadIdx.x;
  int g = blockIdx.x;
  int rs = tid >> 4, c = tid & 15;

  // lower_bound(batch, g) and lower_bound(batch, g+1); batch sorted ascending
  int lo = 0, hi = n_nodes;
  while (lo < hi) { int m = (lo + hi) >> 1; if (batch[m] < g) lo = m + 1; else hi = m; }
  int start = lo;
  hi = n_nodes;
  while (lo < hi) { int m = (lo + hi) >> 1; if (batch[m] < g + 1) lo = m + 1; else hi = m; }
  int end = lo;
  int cnt = end - start;

  float a0 = 0, a1 = 0, a2 = 0, a3 = 0, a4 = 0, a5 = 0, a6 = 0, a7 = 0;
  for (int r = start + rs; r < end; r += 16) {
    uint4 v = *(reinterpret_cast<const uint4*>(xb + (size_t)r * D) + c);
    a0 += bf_lo(v.x); a1 += bf_hi(v.x);
    a2 += bf_lo(v.y); a3 += bf_hi(v.y);
    a4 += bf_lo(v.z); a5 += bf_hi(v.z);
    a6 += bf_lo(v.w); a7 += bf_hi(v.w);
  }
  pp[rs][c * 8 + 0] = a0; pp[rs][c * 8 + 1] = a1;
  pp[rs][c * 8 + 2] = a2; pp[rs][c * 8 + 3] = a3;
  pp[rs][c * 8 + 4] = a4; pp[rs][c * 8 + 5] = a5;
  pp[rs][c * 8 + 6] = a6; pp[rs][c * 8 + 7] = a7;
  __syncthreads();
  for (int s = 8; s >= 1; s >>= 1) {
    if (rs < s) {
      #pragma unroll
      for (int j = 0; j < 8; j++) pp[rs][c * 8 + j] += pp[rs + s][c * 8 + j];
    }
    __syncthreads();
  }
  float inv = 1.0f / fmaxf((float)cnt, 1.0f);
  if (tid < 128) {
    float p = pp[0][tid] * inv;
    #pragma unroll
    for (int j = 0; j < NCLASSES; j++) lg[tid][j] = p * W_fc[tid * NCLASSES + j];
  }
  __syncthreads();
  for (int s = 64; s >= 1; s >>= 1) {
    if (tid < s) {
      #pragma unroll
      for (int j = 0; j < NCLASSES; j++) lg[tid][j] += lg[tid + s][j];
    }
    __syncthreads();
  }
  if (tid == 0) {
    float logits[NCLASSES];
    #pragma unroll
    for (int j = 0; j < NCLASSES; j++) logits[j] = lg[0][j] + b_fc[j];
    float m = logits[0];
    #pragma unroll
    for (int j = 1; j < NCLASSES; j++) m = fmaxf(m, logits[j]);
    float s2 = 0.f;
    #pragma unroll
    for (int j = 0; j < NCLASSES; j++) s2 += expf(logits[j] - m);
    float lse = m + logf(s2);
    #pragma unroll
    for (int j = 0; j < NCLASSES; j++) outp[g * NCLASSES + j] = logits[j] - lse;
  }
}

extern "C" void kernel_launch(void* const* d_in, const int* in_sizes, int n_in,
                              void* d_out, int out_size, void* d_ws, size_t ws_size,
                              hipStream_t stream) {
  const float* x      = (const float*)d_in[0];
  const int*   ei     = (const int*)d_in[1];
  const int*   batch  = (const int*)d_in[2];
  const float* W_rel  = (const float*)d_in[3];
  const float* W_root = (const float*)d_in[4];
  const float* b_rel  = (const float*)d_in[5];
  const float* W_fc   = (const float*)d_in[6];
  const float* b_fc   = (const float*)d_in[7];
  float* outp = (float*)d_out;

  int n_nodes = in_sizes[0] / D;
  int n_edges = in_sizes[1] / 2;
  const int* src = ei;
  const int* dst = ei + n_edges;
  int nb = (n_nodes + 127) / 128;   // 782

  char* ws = (char*)d_ws;
  size_t bb = (size_t)n_nodes * D * sizeof(u16);   // 25.6 MB
  size_t nbts = (size_t)n_nodes * sizeof(int);
  u16* aggb   = (u16*)(ws);
  u16* xba    = (u16*)(ws + bb);
  u16* xbb    = (u16*)(ws + 2 * bb);
  char* p     = ws + 3 * bb;
  u16* Wt     = (u16*)(p);               p += (size_t)6 * D * D * sizeof(u16);
  int* gcnt   = (int*)(p);               p += (size_t)NB * sizeof(int);
  u32* ebuf   = (u32*)(p);               p += (size_t)NB * CAP * sizeof(u32);
  u32* eidx   = (u32*)(p);               p += (size_t)NB * CAP * sizeof(u32);
  int* rowptr = (int*)(p);               p += nbts;
  int* deg    = (int*)(p);               p += nbts;

  // prep: weight transpose+cast, x cast, bucket binning + per-bucket CSR sort
  k_prep_wt<<<(6 * D * D + 255) / 256, 256, 0, stream>>>(W_rel, W_root, Wt);
  long long n8 = (long long)n_nodes * D / 8;
  k_cast0<<<(int)((n8 + 255) / 256), 256, 0, stream>>>(x, xba, n8);
  hipMemsetAsync(gcnt, 0, (size_t)NB * sizeof(int), stream);
  k_bin<<<(n_edges + EPB - 1) / EPB, 256, 0, stream>>>(src, dst, gcnt, ebuf, n_edges, nb);
  k_sort<<<nb, 256, 0, stream>>>(ebuf, gcnt, eidx, rowptr, deg, n_nodes);

  // 3 GraphConv layers
  u16* xc = xba;
  u16* xn = xbb;
  int gemmblk = (n_nodes + 127) / 128;
  for (int l = 0; l < 3; l++) {
    k_gather<<<(n_nodes + 3) / 4, 256, 0, stream>>>(xc, rowptr, deg, eidx, aggb, n_nodes);
    k_gemm_mfma<<<gemmblk, 256, 0, stream>>>(
        aggb, xc, Wt + (size_t)l * D * D, Wt + (size_t)(3 + l) * D * D,
        b_rel + (size_t)l * D, xn, n_nodes);
    u16* t = xc; xc = xn; xn = t;
  }

  // fused pool + head (one block per graph)
  k_poolhead<<<NGRAPHS, 256, 0, stream>>>(xc, batch, W_fc, b_fc, outp, n_nodes);
}